// Round 1
// 236.926 us; speedup vs baseline: 1.0134x; 1.0134x over previous
//
#include <hip/hip_runtime.h>
#include <hip/hip_bf16.h>

#define HS 128
#define NVT 32
#define NN 256

typedef __attribute__((ext_vector_type(8))) short bf16x8;
typedef __attribute__((ext_vector_type(4))) short s16x4;
typedef __attribute__((ext_vector_type(4))) float f32x4;

// ws layout (bytes):
//   [0, 32768)        TABB bf16 [512][32]: rows 0..383 = GW[t][g] at [g][t]; rows 384..511 = G[t][h] at [384+h][t]
//   [32768, 65536)    GIT  bf16 [32][128][4]: (gi_r, gi_z, gi_n, pad) per (t,h); b_hh folded into r,z
//   [65536, 589824)   hgpart float [1024][128]: per-(block-half) partial Hg
#define TABB_OFF 0
#define GIT_OFF  32768
#define HGP_OFF  65536

static __device__ __forceinline__ short f2bs(float f) {
    __hip_bfloat16 h = __float2bfloat16(f);
    short s; __builtin_memcpy(&s, &h, 2);
    return s;
}
static __device__ __forceinline__ float bs2f(short s) {
    __hip_bfloat16 h; __builtin_memcpy(&h, &s, 2);
    return __bfloat162float(h);
}
static __device__ __forceinline__ float sigm(float x) {
    return __builtin_amdgcn_rcpf(1.f + __expf(-x));
}

// ---------------- Kernel A: tiny tables (fp32 inputs) -----------------------
__global__ void __launch_bounds__(512) build_tables(
    const float* __restrict__ W_ih, const float* __restrict__ W_hh,
    const float* __restrict__ b_ih, const float* __restrict__ b_hh,
    const float* __restrict__ Wg,   const float* __restrict__ bg,
    const float* __restrict__ Wm,
    short* __restrict__ TABB, short* __restrict__ GIT)
{
    __shared__ float G_s[HS];
    const int t = blockIdx.x;          // vertex type
    const int j = threadIdx.x;
    if (j < HS) {
        float x = Wg[j * NVT + t] + bg[j];
        G_s[j] = sigm(x) * Wm[j * NVT + t];
    }
    __syncthreads();
    if (j < 384) {
        float acc = 0.f;
        for (int h = 0; h < HS; ++h) acc += G_s[h] * W_hh[j * HS + h];
        TABB[j * NVT + t] = f2bs(acc);                        // GW[t][j] at [j][t]
        float git = W_ih[j * NVT + t] + b_ih[j];
        if (j < 256) git += b_hh[j];                          // fold b_hh for r,z only
        GIT[t * 512 + (j & 127) * 4 + (j >> 7)] = f2bs(git);  // [t][h][gate]
    } else {
        TABB[j * NVT + t] = f2bs(G_s[j - 384]);               // G[t][h] at [384+h][t]
    }
}

// ---------------- Kernel B: fused histogram + MFMA + GRU (half-columns) -----
__global__ void __launch_bounds__(512) dvae_fused(
    const int* __restrict__ node_types, const int* __restrict__ adj,
    const short* __restrict__ TABB, const short* __restrict__ GIT,
    const float* __restrict__ b_hh,
    float* __restrict__ hgpart)
{
    __shared__ int types_s[NN];                  // 1 KB
    __shared__ unsigned tmask[NVT * 8];          // 1 KB  per-type row bitmasks [t][w8]
    __shared__ unsigned short cmask16[16 * 128]; // 4 KB  [rowblock16][local col] bitmask
    __shared__ unsigned cntA[128 * 20];          // 10 KB bf16 count pairs, 16 u32 + 4 pad

    const int bid = blockIdx.x;
    const int b = bid >> 1, vbase = (bid & 1) << 7;   // column half [vbase, vbase+128)
    const int tid = threadIdx.x;                      // 512 threads = 8 waves
    const int wave = tid >> 6, lane = tid & 63;
    const int quad = lane >> 4, col = lane & 15;

    if (tid < NN) types_s[tid] = node_types[b * NN + tid];

    // B fragments + n-gate bias (global, L2-hot) — wave owns h-slice [wave*16, +16)
    bf16x8 bfrag[4];
    #pragma unroll
    for (int g = 0; g < 4; ++g) {
        int jb = (g < 3 ? g * 128 : 384) + wave * 16;
        bfrag[g] = *(const bf16x8*)(TABB + (jb + col) * 32 + quad * 8);
    }
    const int h0 = wave * 16 + col;
    const float bhn = b_hh[256 + h0];    // b_hh n-part stays inside r*(.)

    // ---- phase 1a: adjacency bitmasks, ALL 8 waves, int4 loads ----
    // thread = 4 columns (cg) x 16 rows (rb); wave reads 2 contiguous 512B row-segments/instr
    {
        const int cg = tid & 31, rb = tid >> 5;
        const int4* ap = (const int4*)(adj + (size_t)b * NN * NN + rb * 16 * NN + vbase) + cg;
        unsigned m0 = 0, m1 = 0, m2 = 0, m3 = 0;
        #pragma unroll
        for (int j = 0; j < 16; ++j) {
            int4 a = ap[j * (NN / 4)];
            m0 |= ((unsigned)a.x) << j;
            m1 |= ((unsigned)a.y) << j;
            m2 |= ((unsigned)a.z) << j;
            m3 |= ((unsigned)a.w) << j;
        }
        uint2 pk;                                   // cols 4cg..4cg+3 as 16-bit masks
        pk.x = m0 | (m1 << 16);
        pk.y = m2 | (m3 << 16);
        *(uint2*)&cmask16[rb * 128 + cg * 4] = pk;  // 8B-aligned b64 write
    }
    __syncthreads();                     // types_s + cmask16 ready

    // ---- phase 1b: per-type row bitmasks ----
    if (tid < NN) {
        int t = tid >> 3, w8 = tid & 7;
        unsigned mw = 0;
        #pragma unroll
        for (int k = 0; k < 32; ++k)
            mw |= ((unsigned)(types_s[w8 * 32 + k] == t)) << k;
        tmask[tid] = mw;
    }
    __syncthreads();

    // ---- phase 1c: popcount histogram, ALL 8 waves (4 type-pairs each) ----
    {
        const int v = tid & 127, tpg = tid >> 7;    // tpg wave-uniform -> tmask broadcasts
        unsigned cb[8];
        #pragma unroll
        for (int w = 0; w < 8; ++w)
            cb[w] = (unsigned)cmask16[2 * w * 128 + v]
                  | ((unsigned)cmask16[(2 * w + 1) * 128 + v] << 16);
        #pragma unroll
        for (int k = 0; k < 4; ++k) {
            int tp = tpg * 4 + k;
            const uint4* m0p = (const uint4*)&tmask[(2 * tp) * 8];
            const uint4* m1p = (const uint4*)&tmask[(2 * tp + 1) * 8];
            uint4 ma = m0p[0], mb = m0p[1], mc = m1p[0], md = m1p[1];
            unsigned c0 = __popc(cb[0] & ma.x) + __popc(cb[1] & ma.y)
                        + __popc(cb[2] & ma.z) + __popc(cb[3] & ma.w)
                        + __popc(cb[4] & mb.x) + __popc(cb[5] & mb.y)
                        + __popc(cb[6] & mb.z) + __popc(cb[7] & mb.w);
            unsigned c1 = __popc(cb[0] & mc.x) + __popc(cb[1] & mc.y)
                        + __popc(cb[2] & mc.z) + __popc(cb[3] & mc.w)
                        + __popc(cb[4] & md.x) + __popc(cb[5] & md.y)
                        + __popc(cb[6] & md.z) + __popc(cb[7] & md.w);
            // counts <= 255: bf16 exact = top 16 bits of fp32
            unsigned p = (__float_as_uint((float)c0) >> 16)
                       | (__float_as_uint((float)c1) & 0xFFFF0000u);
            cntA[v * 20 + tp] = p;
        }
    }
    __syncthreads();

    // ---- phase 2: 8 m-tiles, in-register GRU epilogue, all 8 waves ----
    float hg = 0.f;
    for (int m = 0; m < 8; ++m) {
        bf16x8 afrag = *(const bf16x8*)(cntA + (m * 16 + col) * 20 + quad * 4);
        f32x4 acc[4];
        #pragma unroll
        for (int g = 0; g < 4; ++g)
            acc[g] = __builtin_amdgcn_mfma_f32_16x16x32_bf16(
                afrag, bfrag[g], (f32x4){0.f, 0.f, 0.f, 0.f}, 0, 0, 0);
        // C/D: col = n (h-offset), row = quad*4 + r (v within tile)
        #pragma unroll
        for (int r = 0; r < 4; ++r) {
            int vv = vbase + m * 16 + quad * 4 + r;
            int tv = types_s[vv];
            s16x4 gv = *(const s16x4*)(GIT + tv * 512 + h0 * 4);   // L2-hot 32KB table
            float gir = bs2f(gv[0]);
            float giz = bs2f(gv[1]);
            float gin = bs2f(gv[2]);
            float rr = sigm(gir + acc[0][r]);
            float zz = sigm(giz + acc[1][r]);
            float x2 = gin + rr * (acc[2][r] + bhn);
            float nt = 1.f - 2.f * __builtin_amdgcn_rcpf(1.f + __expf(2.f * x2));
            float msk = (vv >= 1 && vv < NN - 1) ? 1.f : 0.f;      // Hg: v in [1,254]
            hg += msk * ((1.f - zz) * nt + zz * acc[3][r]);
        }
    }
    // reduce across the 4 quads (same h0, different v-rows)
    hg += __shfl_xor(hg, 16);
    hg += __shfl_xor(hg, 32);
    if (lane < 16) hgpart[bid * HS + h0] = hg;   // each h owned by exactly one wave
}

// ---------------- Kernel C: combine halves + mu/logvar readout --------------
__global__ void __launch_bounds__(128) dvae_readout(
    const float* __restrict__ hgpart,
    const float* __restrict__ W1, const float* __restrict__ b1,
    const float* __restrict__ W2, const float* __restrict__ b2,
    float* __restrict__ out)
{
    __shared__ float hg_s[HS];
    const int b = blockIdx.x, tid = threadIdx.x;
    hg_s[tid] = hgpart[(2 * b) * HS + tid] + hgpart[(2 * b + 1) * HS + tid];
    __syncthreads();
    const int which = tid >> 6, z = tid & 63;
    const float* W = which ? W2 : W1;
    float acc = which ? b2[z] : b1[z];
    const float4* Wv = (const float4*)(W + z * HS);
    #pragma unroll
    for (int i = 0; i < 32; ++i) {
        float4 ww = Wv[i];
        acc += hg_s[4 * i] * ww.x + hg_s[4 * i + 1] * ww.y
             + hg_s[4 * i + 2] * ww.z + hg_s[4 * i + 3] * ww.w;
    }
    out[which * 32768 + b * 64 + z] = acc;
}

extern "C" void kernel_launch(void* const* d_in, const int* in_sizes, int n_in,
                              void* d_out, int out_size, void* d_ws, size_t ws_size,
                              hipStream_t stream)
{
    const int* node_types = (const int*)d_in[0];
    const int* adj        = (const int*)d_in[1];
    const float* W_ih = (const float*)d_in[2];
    const float* W_hh = (const float*)d_in[3];
    const float* b_ih = (const float*)d_in[4];
    const float* b_hh = (const float*)d_in[5];
    const float* Wg   = (const float*)d_in[6];
    const float* bg   = (const float*)d_in[7];
    const float* Wm   = (const float*)d_in[8];
    const float* W1   = (const float*)d_in[9];
    const float* b1   = (const float*)d_in[10];
    const float* W2   = (const float*)d_in[11];
    const float* b2   = (const float*)d_in[12];

    char* ws = (char*)d_ws;
    short* TABB   = (short*)(ws + TABB_OFF);
    short* GIT    = (short*)(ws + GIT_OFF);
    float* hgpart = (float*)(ws + HGP_OFF);
    float* out    = (float*)d_out;

    build_tables<<<dim3(32), dim3(512), 0, stream>>>(W_ih, W_hh, b_ih, b_hh, Wg, bg, Wm, TABB, GIT);
    dvae_fused<<<dim3(1024), dim3(512), 0, stream>>>(node_types, adj, TABB, GIT, b_hh, hgpart);
    dvae_readout<<<dim3(512), dim3(128), 0, stream>>>(hgpart, W1, b1, W2, b2, out);
}